// Round 3
// baseline (462.705 us; speedup 1.0000x reference)
//
#include <hip/hip_runtime.h>
#include <hip/hip_fp16.h>

// Problem dims (fixed by reference)
#define S_LEN 1024
#define BSZ   32
#define IN_DIM 1024
#define HID   1024
#define MDIM  (S_LEN*BSZ)   // 32768 GEMM rows (relabeled m' = b*1024 + s)
#define NDIM  (2*HID)       // 2048 GEMM cols (z | f interleaved in 16-row groups)
#define KDIM  IN_DIM        // 1024

typedef __attribute__((ext_vector_type(8))) _Float16 half8;
typedef __attribute__((ext_vector_type(2))) _Float16 half2v;
typedef __attribute__((ext_vector_type(4))) float    floatx4;

// ---------------- fp32 -> fp16 conversion, x transposed to rows m' = b*1024+s ----------------
__global__ void cvt_x_kernel(const float* __restrict__ x, _Float16* __restrict__ xh) {
    int idx = blockIdx.x * blockDim.x + threadIdx.x;   // one half8 (8 elems) per thread
    int e0 = idx * 8;
    int row = e0 >> 10;            // input row = s*32 + b
    int col = e0 & 1023;
    int s = row >> 5, b = row & 31;
    const float4* src = (const float4*)(x + e0);
    float4 a = src[0], bb = src[1];
    half8 h;
    h[0] = (_Float16)a.x;  h[1] = (_Float16)a.y;  h[2] = (_Float16)a.z;  h[3] = (_Float16)a.w;
    h[4] = (_Float16)bb.x; h[5] = (_Float16)bb.y; h[6] = (_Float16)bb.z; h[7] = (_Float16)bb.w;
    *(half8*)(xh + (((size_t)((b << 10) | s)) << 10) + col) = h;
}

// Interleaved weight layout: out row r: g=r>>5, sub=r&31; sub<16 -> z row g*16+sub, else f row g*16+sub-16.
__global__ void cvt_w_kernel(const float* __restrict__ wz, const float* __restrict__ wf,
                             _Float16* __restrict__ wh) {
    int idx = blockIdx.x * blockDim.x + threadIdx.x;
    int e0 = idx * 8;
    int r   = e0 >> 10;
    int col = e0 & 1023;
    int g = r >> 5, sub = r & 31;
    const float* src = (sub < 16)
        ? wz + ((size_t)(g * 16 + sub)      * KDIM + col)
        : wf + ((size_t)(g * 16 + sub - 16) * KDIM + col);
    const float4* s4 = (const float4*)src;
    float4 a = s4[0], b = s4[1];
    half8 h;
    h[0] = (_Float16)a.x; h[1] = (_Float16)a.y; h[2] = (_Float16)a.z; h[3] = (_Float16)a.w;
    h[4] = (_Float16)b.x; h[5] = (_Float16)b.y; h[6] = (_Float16)b.z; h[7] = (_Float16)b.w;
    *((half8*)wh + idx) = h;
}

// ---------------- fp16 MFMA GEMM -> transposed packed pre-acts zfT[(b*1024+h)*1024 + s] ----------------
#define BM 128
#define BN 128
#define BK 32

__global__ void gemm_f16_kernel(const _Float16* __restrict__ A, const _Float16* __restrict__ B,
                                uint* __restrict__ zfT) {
    __shared__ _Float16 As[BM * BK];   // row stride 64B; k-chunks XOR-swizzled by (row>>1)&3
    __shared__ _Float16 Bs[BN * BK];

    const int tid  = threadIdx.x;
    const int lane = tid & 63;
    const int wv   = tid >> 6;

    // XCD-aware swizzle: xcd = flat&7 owns whole m-tiles; n iterates fastest within an XCD.
    const int flat   = blockIdx.x;
    const int xcd    = flat & 7;
    const int local  = flat >> 3;
    const int tile_m = (local >> 4) * 8 + xcd;
    const int tile_n = local & 15;
    const int m0  = tile_m * BM;
    const int n0g = tile_n * BN;

    const int wm = (wv >> 1) * 64;
    const int wn = (wv & 1) * 64;

    floatx4 acc[4][4] = {};

    const int fr = lane & 15;
    const int fc = lane >> 4;          // fragment k-chunk index 0..3 (8 halves each)

    for (int k0 = 0; k0 < KDIM; k0 += BK) {
        #pragma unroll
        for (int i = 0; i < 2; ++i) {
            int cb  = i * 256 + wv * 64;       // wave-uniform chunk base
            int c   = cb + lane;
            int row = c >> 2;
            int kc  = ((c & 3) ^ ((row >> 1) & 3)) * 8;   // bank-conflict swizzle
            const _Float16* gp = A + (size_t)(m0 + row) * KDIM + k0 + kc;
            __builtin_amdgcn_global_load_lds(
                (const __attribute__((address_space(1))) void*)gp,
                (__attribute__((address_space(3))) void*)(As + (size_t)cb * 8), 16, 0, 0);
            const _Float16* gq = B + (size_t)(n0g + row) * KDIM + k0 + kc;
            __builtin_amdgcn_global_load_lds(
                (const __attribute__((address_space(1))) void*)gq,
                (__attribute__((address_space(3))) void*)(Bs + (size_t)cb * 8), 16, 0, 0);
        }
        __syncthreads();

        half8 af[4], bf[4];
        #pragma unroll
        for (int i = 0; i < 4; ++i) {
            int R = wm + i * 16 + fr;
            af[i] = *(const half8*)(As + R * BK + (fc ^ ((R >> 1) & 3)) * 8);
        }
        #pragma unroll
        for (int j = 0; j < 4; ++j) {
            int R = wn + j * 16 + fr;
            bf[j] = *(const half8*)(Bs + R * BK + (fc ^ ((R >> 1) & 3)) * 8);
        }

        #pragma unroll
        for (int i = 0; i < 4; ++i)
            #pragma unroll
            for (int j = 0; j < 4; ++j)
                acc[i][j] = __builtin_amdgcn_mfma_f32_16x16x32_f16(af[i], bf[j], acc[i][j], 0, 0, 0);
        __syncthreads();
    }

    // Epilogue: C/D layout col=lane&15, row=(lane>>4)*4+reg [m89/m91].
    // GEMM row m' = b*1024+s (b uniform per block); col-tile pair (2p,2p+1) = (z,f) of one h.
    // Store uint4 = 4 consecutive s for fixed (b,h).
    const int orow  = (lane >> 4) * 4;
    const int ocol  = lane & 15;
    const int gbase = (n0g + wn) >> 5;
    const int b_blk = m0 >> 10;
    const int sbase = (m0 & 1023) + wm;
    #pragma unroll
    for (int i = 0; i < 4; ++i)
        #pragma unroll
        for (int p = 0; p < 2; ++p) {
            int h = (gbase + p) * 16 + ocol;
            int s = sbase + i * 16 + orow;
            uint4 v;
            half2v e0; e0[0] = (_Float16)acc[i][2*p][0]; e0[1] = (_Float16)acc[i][2*p+1][0];
            half2v e1; e1[0] = (_Float16)acc[i][2*p][1]; e1[1] = (_Float16)acc[i][2*p+1][1];
            half2v e2; e2[0] = (_Float16)acc[i][2*p][2]; e2[1] = (_Float16)acc[i][2*p+1][2];
            half2v e3; e3[0] = (_Float16)acc[i][2*p][3]; e3[1] = (_Float16)acc[i][2*p+1][3];
            v.x = __builtin_bit_cast(uint, e0);
            v.y = __builtin_bit_cast(uint, e1);
            v.z = __builtin_bit_cast(uint, e2);
            v.w = __builtin_bit_cast(uint, e3);
            *(uint4*)(zfT + (((size_t)((b_blk << 10) + h)) << 10) + s) = v;
        }
}

// ---------------- sequential scan, one thread per (b,h), contiguous [t][s] reads ----------------
#define UNR 64
#define NG  (UNR / 4)
__global__ __launch_bounds__(64) void scan_kernel(
    const uint* __restrict__ zfT, float* __restrict__ out,
    const float* __restrict__ state,
    const float* __restrict__ wvz, const float* __restrict__ wvf,
    const float* __restrict__ bz, const float* __restrict__ bfv) {
    const int t = blockIdx.x * 64 + threadIdx.x;   // t = b*1024 + h
    const int h = t & (HID - 1);

    float cell = state[t];
    const float az = wvz[h], afc = wvf[h], cz = bz[h], cf = bfv[h];

    const uint4* p4 = (const uint4*)zfT + (size_t)t * (S_LEN / 4);
    float* po = out + t;

    uint4 buf[NG], nb[NG];
    #pragma unroll
    for (int g = 0; g < NG; ++g) buf[g] = p4[g];

    for (int s0 = 0; s0 < S_LEN; s0 += UNR) {
        if (s0 + UNR < S_LEN) {
            const uint4* pn = p4 + (s0 + UNR) / 4;
            #pragma unroll
            for (int g = 0; g < NG; ++g) nb[g] = pn[g];
        }
        #pragma unroll
        for (int g = 0; g < NG; ++g) {
            uint ww[4] = {buf[g].x, buf[g].y, buf[g].z, buf[g].w};
            #pragma unroll
            for (int e = 0; e < 4; ++e) {
                half2v h2 = __builtin_bit_cast(half2v, ww[e]);
                float zpre = (float)h2[0] + az * cell + cz;
                float fpre = (float)h2[1] + afc * cell + cf;
                float ez = __expf(2.0f * zpre);
                float zp = (ez - 1.0f) * __builtin_amdgcn_rcpf(ez + 1.0f);   // tanh
                float fp = __builtin_amdgcn_rcpf(1.0f + __expf(-fpre));      // sigmoid
                cell = fmaf(cell - zp, fp, zp);                               // c*f + (1-f)*z
                po[(size_t)(s0 + g * 4 + e) * (BSZ * HID)] = cell;
            }
        }
        #pragma unroll
        for (int g = 0; g < NG; ++g) buf[g] = nb[g];
    }
}

extern "C" void kernel_launch(void* const* d_in, const int* in_sizes, int n_in,
                              void* d_out, int out_size, void* d_ws, size_t ws_size,
                              hipStream_t stream) {
    const float* x      = (const float*)d_in[0];
    const float* state  = (const float*)d_in[1];
    const float* wm_z   = (const float*)d_in[2];
    const float* wm_f   = (const float*)d_in[3];
    const float* wv_z   = (const float*)d_in[4];
    const float* wv_f   = (const float*)d_in[5];
    const float* bias_z = (const float*)d_in[6];
    const float* bias_f = (const float*)d_in[7];
    float* out = (float*)d_out;

    // workspace layout: xh 64MB | wh 4MB | zfT 128MB  (total 196MB)
    char* ws = (char*)d_ws;
    _Float16* xh = (_Float16*)ws;
    _Float16* wh = (_Float16*)(ws + (size_t)MDIM * KDIM * sizeof(_Float16));
    uint* zfT    = (uint*)(ws + (size_t)MDIM * KDIM * sizeof(_Float16)
                              + (size_t)NDIM * KDIM * sizeof(_Float16));

    cvt_x_kernel<<<(MDIM * KDIM) / (256 * 8), 256, 0, stream>>>(x, xh);
    cvt_w_kernel<<<(NDIM * KDIM) / (256 * 8), 256, 0, stream>>>(wm_z, wm_f, wh);

    gemm_f16_kernel<<<(MDIM / BM) * (NDIM / BN), 256, 0, stream>>>(xh, wh, zfT);

    scan_kernel<<<MDIM / 64, 64, 0, stream>>>(zfT, out, state, wv_z, wv_f, bias_z, bias_f);
}